// Round 1
// baseline (707.249 us; speedup 1.0000x reference)
//
#include <hip/hip_runtime.h>
#include <math.h>

#define PIX 4096

__device__ __forceinline__ void waveRed2(float& a, float& b) {
#pragma unroll
  for (int off = 32; off; off >>= 1) {
    a += __shfl_down(a, off);
    b += __shfl_down(b, off);
  }
}

// out[b, ot+o, pt+p] = [relu?](sum_c W1[o,c]*A1[b,c,p]) [+ sum_c W2[o,c]*A2[b,c,p]]
__global__ __launch_bounds__(256, 2) void gemm1x1(
    const float* __restrict__ W1, const float* __restrict__ A1base, int K1, int relu1,
    const float* __restrict__ W2, const float* __restrict__ A2base, int K2,
    float* __restrict__ out)
{
  __shared__ float Wt[16][128];  // [c][o] transposed weight tile
  __shared__ float At[16][128];  // [c][p] activation tile
  const int t  = threadIdx.x;
  const int pt = blockIdx.x * 128;
  const int ot = blockIdx.y * 128;
  const int b  = blockIdx.z;
  const int o0 = (t >> 4) * 8;
  const int p0 = (t & 15) * 8;

  float acc[8][8];
#pragma unroll
  for (int i = 0; i < 8; ++i)
#pragma unroll
    for (int j = 0; j < 8; ++j) acc[i][j] = 0.f;

  for (int pass = 0; pass < 2; ++pass) {
    const float* W;
    const float* A;
    int K;
    if (pass == 0) {
      W = W1; A = A1base + (size_t)b * K1 * PIX; K = K1;
    } else {
      if (!W2) break;
      W = W2; A = A2base + (size_t)b * K2 * PIX; K = K2;
    }
    for (int kb = 0; kb < K; kb += 16) {
      // stage: 128x16 W tile (transposed into LDS) + 16x128 A tile
#pragma unroll
      for (int r = 0; r < 2; ++r) {
        int idx = t + r * 256;           // float4 id, 0..511
        int o = idx >> 2, c4 = idx & 3;  // W: 4 float4 per o-row
        float4 w = *(const float4*)&W[(size_t)(ot + o) * K + kb + c4 * 4];
        Wt[c4 * 4 + 0][o] = w.x;
        Wt[c4 * 4 + 1][o] = w.y;
        Wt[c4 * 4 + 2][o] = w.z;
        Wt[c4 * 4 + 3][o] = w.w;
        int cr = idx >> 5, p4 = idx & 31;  // A: 32 float4 per c-row
        *(float4*)&At[cr][p4 * 4] =
            *(const float4*)&A[(size_t)(kb + cr) * PIX + pt + p4 * 4];
      }
      __syncthreads();
#pragma unroll
      for (int kk = 0; kk < 16; ++kk) {
        float4 w0 = *(const float4*)&Wt[kk][o0];
        float4 w1 = *(const float4*)&Wt[kk][o0 + 4];
        float4 a0 = *(const float4*)&At[kk][p0];
        float4 a1 = *(const float4*)&At[kk][p0 + 4];
        float wv[8] = {w0.x, w0.y, w0.z, w0.w, w1.x, w1.y, w1.z, w1.w};
        float av[8] = {a0.x, a0.y, a0.z, a0.w, a1.x, a1.y, a1.z, a1.w};
#pragma unroll
        for (int i = 0; i < 8; ++i)
#pragma unroll
          for (int j = 0; j < 8; ++j)
            acc[i][j] = fmaf(wv[i], av[j], acc[i][j]);
      }
      __syncthreads();
    }
    if (pass == 0 && relu1) {
#pragma unroll
      for (int i = 0; i < 8; ++i)
#pragma unroll
        for (int j = 0; j < 8; ++j) acc[i][j] = fmaxf(acc[i][j], 0.f);
    }
  }
#pragma unroll
  for (int i = 0; i < 8; ++i) {
    size_t row = (size_t)(b * 512 + ot + o0 + i) * PIX + pt + p0;
    *(float4*)&out[row]     = make_float4(acc[i][0], acc[i][1], acc[i][2], acc[i][3]);
    *(float4*)&out[row + 4] = make_float4(acc[i][4], acc[i][5], acc[i][6], acc[i][7]);
  }
}

// One block per (b,o) plane. phi0 comes in via ob (written by gemm), z via zb.
// Runs all 10 Chan-Vese iterations in LDS, writes sigmoid(phi) to ob.
__global__ __launch_bounds__(256) void chanvese(
    const float* __restrict__ zb, float* __restrict__ ob,
    const float* __restrict__ dtp, const float* __restrict__ lamp)
{
  __shared__ float phi_s[4096];
  __shared__ float nx_s[4096];
  __shared__ float ny_s[4096];
  __shared__ float red[8];
  const int t = threadIdx.x;
  const size_t base = (size_t)blockIdx.x * PIX;
  const float dtv = dtp[0];
  const float lam = lamp[0];
  const float INV_PI = 0.31830988618379067f;

  float I[16], phi_r[16];
  float sI = 0.f;
#pragma unroll
  for (int k = 0; k < 16; ++k) {
    int p = t + (k << 8);
    I[k] = zb[base + p];
    sI += I[k];
    float ph = ob[base + p];
    phi_r[k] = ph;
    phi_s[p] = ph;
  }
  float dummy = 0.f;
  waveRed2(sI, dummy);
  if ((t & 63) == 0) red[t >> 6] = sI;
  __syncthreads();
  const float sumI = red[0] + red[1] + red[2] + red[3];
  __syncthreads();

  for (int it = 0; it < 10; ++it) {
    float sH = 0.f, sIH = 0.f;
#pragma unroll
    for (int k = 0; k < 16; ++k) {
      int p = t + (k << 8);
      int w = p & 63, h = p >> 6;
      float c = phi_r[k];
      float l = w        ? phi_s[p - 1]  : c;
      float r = (w < 63) ? phi_s[p + 1]  : c;
      float u = h        ? phi_s[p - 64] : c;
      float d = (h < 63) ? phi_s[p + 64] : c;
      float fx = (w == 0 || w == 63) ? 1.f : 0.5f;  // jnp.gradient edge scheme
      float fy = (h == 0 || h == 63) ? 1.f : 0.5f;
      float px = (r - l) * fx;
      float py = (d - u) * fy;
      float rn = rsqrtf(px * px + py * py + 1e-8f);
      nx_s[p] = px * rn;
      ny_s[p] = py * rn;
      float Hs = 0.5f + INV_PI * atanf(c);
      sH += Hs;
      sIH += I[k] * Hs;
    }
    waveRed2(sH, sIH);
    if ((t & 63) == 0) { red[(t >> 6) * 2] = sH; red[(t >> 6) * 2 + 1] = sIH; }
    __syncthreads();
    float a1   = red[0] + red[2] + red[4] + red[6];
    float sIHt = red[1] + red[3] + red[5] + red[7];
    float c1 = sIHt / (a1 + 1e-8f);
    float c2 = (sumI - sIHt) / (4096.f - a1 + 1e-8f);
#pragma unroll
    for (int k = 0; k < 16; ++k) {
      int p = t + (k << 8);
      int w = p & 63, h = p >> 6;
      float nl = w        ? nx_s[p - 1]  : nx_s[p];
      float nr = (w < 63) ? nx_s[p + 1]  : nx_s[p];
      float nu = h        ? ny_s[p - 64] : ny_s[p];
      float nd = (h < 63) ? ny_s[p + 64] : ny_s[p];
      float fx = (w == 0 || w == 63) ? 1.f : 0.5f;
      float fy = (h == 0 || h == 63) ? 1.f : 0.5f;
      float curv = (nr - nl) * fx + (nd - nu) * fy;
      float c = phi_r[k];
      float delta = INV_PI / (c * c + 1.f);
      float d1 = I[k] - c1, d2 = I[k] - c2;
      float force = curv + lam * (d2 * d2 - d1 * d1);
      float np = c + dtv * delta * force;
      phi_r[k] = np;
      phi_s[p] = np;
    }
    __syncthreads();
  }
#pragma unroll
  for (int k = 0; k < 16; ++k) {
    int p = t + (k << 8);
    ob[base + p] = 1.f / (1.f + expf(-phi_r[k]));
  }
}

extern "C" void kernel_launch(void* const* d_in, const int* in_sizes, int n_in,
                              void* d_out, int out_size, void* d_ws, size_t ws_size,
                              hipStream_t stream)
{
  const float* contour = (const float*)d_in[0];
  const float* g       = (const float*)d_in[1];
  const float* x       = (const float*)d_in[2];
  const float* dt      = (const float*)d_in[3];
  const float* lam     = (const float*)d_in[4];
  const float* g_w     = (const float*)d_in[5];
  const float* x_w     = (const float*)d_in[6];
  const float* c_w     = (const float*)d_in[7];
  float* out = (float*)d_out;
  float* z   = (float*)d_ws;  // [8,512,64,64] f32 = 67 MB

  dim3 grid(32, 4, 8), blk(256);
  // z = relu(g * g_w^T) + x * x_w^T
  gemm1x1<<<grid, blk, 0, stream>>>(g_w, g, 256, 1, x_w, x, 512, z);
  // phi0 = contour * c_w^T  -> d_out (iterated in place by chanvese)
  gemm1x1<<<grid, blk, 0, stream>>>(c_w, contour, 256, 0, nullptr, nullptr, 0, out);
  // 10 Chan-Vese iterations + sigmoid, one block per (b,o) plane
  chanvese<<<dim3(4096), blk, 0, stream>>>(z, out, dt, lam);
}

// Round 2
// 406.774 us; speedup vs baseline: 1.7387x; 1.7387x over previous
//
#include <hip/hip_runtime.h>
#include <math.h>

#define PIX 4096
#define O_CH 512

typedef __attribute__((ext_vector_type(8))) short s16x8;
typedef __attribute__((ext_vector_type(4))) float f32x4;

__device__ __forceinline__ ushort f2bf(float f) {
  unsigned u = __float_as_uint(f);
  return (ushort)((u + 0x7fffu + ((u >> 16) & 1u)) >> 16);
}
__device__ __forceinline__ float bf2f(ushort h) {
  return __uint_as_float(((unsigned)h) << 16);
}

// ---------------- MFMA GEMM (split-bf16, ~fp32 accurate) ----------------
// out[b, ob+o, pb+p] = [relu?](sum_c W1[o,c]A1[b,c,p]) [+ sum_c W2[o,c]A2[b,c,p]]
__global__ __launch_bounds__(256, 2) void mfma_gemm(
    const float* __restrict__ W1, const float* __restrict__ A1b, int K1, int relu1,
    const float* __restrict__ W2, const float* __restrict__ A2b, int K2,
    float* __restrict__ out)
{
  __shared__ ushort WHs[8192], WLs[8192], AHs[8192], ALs[8192];  // 64 KB
  const int t = threadIdx.x;
  const int lane = t & 63, wave = t >> 6;
  const int wm = wave >> 1, wn = wave & 1;          // 2x2 waves of 64x64
  const int rowA = lane & 15, kg = lane >> 4;
  const int pb = blockIdx.x * 128, ob = blockIdx.y * 128, b = blockIdx.z;

  f32x4 acc[4][4];
#pragma unroll
  for (int mi = 0; mi < 4; ++mi)
#pragma unroll
    for (int ni = 0; ni < 4; ++ni) acc[mi][ni] = (f32x4){0.f, 0.f, 0.f, 0.f};

  for (int pass = 0; pass < 2; ++pass) {
    if (pass == 1 && W2 == nullptr) break;
    const float* W = pass ? W2 : W1;
    const int K = pass ? K2 : K1;
    const float* A = (pass ? A2b : A1b) + (size_t)b * K * PIX;

    for (int kb = 0; kb < K; kb += 64) {
      // ---- stage W tile [128 o][64 k] as hi/lo bf16, XOR-swizzled ----
      {
        const int o_r = t >> 1, hf = t & 1;
        const float* wrow = W + (size_t)(ob + o_r) * K + kb + hf * 32;
#pragma unroll
        for (int i = 0; i < 8; ++i) {
          float4 v = *(const float4*)(wrow + i * 4);
          ushort h0 = f2bf(v.x), h1 = f2bf(v.y), h2 = f2bf(v.z), h3 = f2bf(v.w);
          ushort l0 = f2bf(v.x - bf2f(h0)), l1 = f2bf(v.y - bf2f(h1));
          ushort l2 = f2bf(v.z - bf2f(h2)), l3 = f2bf(v.w - bf2f(h3));
          int grp = hf * 4 + (i >> 1);
          int idx = o_r * 64 + ((grp ^ (o_r & 7)) << 3) + (i & 1) * 4;
          *(ushort4*)&WHs[idx] = make_ushort4(h0, h1, h2, h3);
          *(ushort4*)&WLs[idx] = make_ushort4(l0, l1, l2, l3);
        }
      }
      // ---- stage A tile transposed to [128 p][64 k], hi/lo, swizzled ----
#pragma unroll
      for (int ph = 0; ph < 2; ++ph) {
        const int rp = ph * 64 + lane;
        const float* ac = A + (size_t)kb * PIX + pb + rp;
#pragma unroll
        for (int ch = 0; ch < 2; ++ch) {
          const int kloc0 = ch * 32 + wave * 8;
          float v[8];
#pragma unroll
          for (int j = 0; j < 8; ++j) v[j] = ac[(size_t)(kloc0 + j) * PIX];
          ushort hs[8], lsv[8];
#pragma unroll
          for (int j = 0; j < 8; ++j) {
            ushort hb = f2bf(v[j]);
            hs[j] = hb;
            lsv[j] = f2bf(v[j] - bf2f(hb));
          }
          int grp = ch * 4 + wave;
          int idx = rp * 64 + ((grp ^ (rp & 7)) << 3);
          *(ushort4*)&AHs[idx]     = make_ushort4(hs[0], hs[1], hs[2], hs[3]);
          *(ushort4*)&AHs[idx + 4] = make_ushort4(hs[4], hs[5], hs[6], hs[7]);
          *(ushort4*)&ALs[idx]     = make_ushort4(lsv[0], lsv[1], lsv[2], lsv[3]);
          *(ushort4*)&ALs[idx + 4] = make_ushort4(lsv[4], lsv[5], lsv[6], lsv[7]);
        }
      }
      __syncthreads();
      // ---- compute: 3 split-passes, 96 MFMA per wave per K-step ----
#pragma unroll
      for (int ks = 0; ks < 2; ++ks) {
        s16x8 wh[4], wlv[4], ah[4], alv[4];
#pragma unroll
        for (int mi = 0; mi < 4; ++mi) {
          int row = wm * 64 + mi * 16 + rowA;
          int idx = row * 64 + (((ks * 4 + kg) ^ (row & 7)) << 3);
          wh[mi]  = *(const s16x8*)&WHs[idx];
          wlv[mi] = *(const s16x8*)&WLs[idx];
        }
#pragma unroll
        for (int ni = 0; ni < 4; ++ni) {
          int row = wn * 64 + ni * 16 + rowA;
          int idx = row * 64 + (((ks * 4 + kg) ^ (row & 7)) << 3);
          ah[ni]  = *(const s16x8*)&AHs[idx];
          alv[ni] = *(const s16x8*)&ALs[idx];
        }
#pragma unroll
        for (int mi = 0; mi < 4; ++mi)
#pragma unroll
          for (int ni = 0; ni < 4; ++ni) {
            acc[mi][ni] = __builtin_amdgcn_mfma_f32_16x16x32_bf16(wh[mi],  ah[ni],  acc[mi][ni], 0, 0, 0);
            acc[mi][ni] = __builtin_amdgcn_mfma_f32_16x16x32_bf16(wh[mi],  alv[ni], acc[mi][ni], 0, 0, 0);
            acc[mi][ni] = __builtin_amdgcn_mfma_f32_16x16x32_bf16(wlv[mi], ah[ni],  acc[mi][ni], 0, 0, 0);
          }
      }
      __syncthreads();
    }
    if (pass == 0 && relu1) {
#pragma unroll
      for (int mi = 0; mi < 4; ++mi)
#pragma unroll
        for (int ni = 0; ni < 4; ++ni)
#pragma unroll
          for (int r = 0; r < 4; ++r) acc[mi][ni][r] = fmaxf(acc[mi][ni][r], 0.f);
    }
  }
  // epilogue: C/D layout col=lane&15, row=(lane>>4)*4+reg
  const int orow = (lane >> 4) * 4, pcol = lane & 15;
#pragma unroll
  for (int mi = 0; mi < 4; ++mi)
#pragma unroll
    for (int ni = 0; ni < 4; ++ni)
#pragma unroll
      for (int r = 0; r < 4; ++r)
        out[((size_t)b * O_CH + ob + wm * 64 + mi * 16 + orow + r) * PIX +
            pb + wn * 64 + ni * 16 + pcol] = acc[mi][ni][r];
}

// ---------------- Chan-Vese: 10 iters fully in LDS/registers ----------------
__device__ __forceinline__ float fast_atan(float x) {
  // A&S 4.4.49 deg-9 minimax on [0,1], |err|<=1e-5; range-extend via pi/2-atan(1/x)
  float a = __builtin_fabsf(x);
  float inv = __builtin_amdgcn_rcpf(a);
  bool big = a > 1.f;
  float tt = big ? inv : a;
  float t2 = tt * tt;
  float p = fmaf(t2, 0.0208351f, -0.0851330f);
  p = fmaf(t2, p, 0.1801410f);
  p = fmaf(t2, p, -0.3302995f);
  p = fmaf(t2, p, 0.9998660f);
  p = p * tt;
  float r = big ? (1.57079632679f - p) : p;
  return __builtin_copysignf(r, x);
}

__global__ __launch_bounds__(256, 4) void chanvese(
    const float* __restrict__ zb, float* __restrict__ ob,
    const float* __restrict__ dtp, const float* __restrict__ lamp)
{
  __shared__ float phi_p[66 * 64];  // top/bottom halo rows (replicated)
  __shared__ float ny_p[66 * 64];
  __shared__ float red[8];
  const int t = threadIdx.x;
  const int w = t & 63, h0 = t >> 6;  // lane == column; wave == 1 full row per k
  const size_t base = (size_t)blockIdx.x * PIX;
  const float dtv = dtp[0], lam = lamp[0];
  const float INV_PI = 0.31830988618379067f;
  const float dtpi = dtv * INV_PI;
  const float fx = (w == 0 || w == 63) ? 1.f : 0.5f;
  const float fy0 = (h0 == 0) ? 1.f : 0.5f;
  const float fy15 = (h0 == 3) ? 1.f : 0.5f;
  const int wl = (w == 0) ? 0 : w - 1;
  const int wr = (w == 63) ? 63 : w + 1;
  const int ib = h0 * 64 + w;  // padded index of row (h-1)+1 at k=0

  float I[16], phi_r[16], nx_r[16];
  float sI = 0.f;
#pragma unroll
  for (int k = 0; k < 16; ++k) {
    const int p = t + (k << 8);
    I[k] = zb[base + p];
    sI += I[k];
    float ph = ob[base + p];
    phi_r[k] = ph;
    phi_p[ib + 64 + k * 256] = ph;
  }
  if (h0 == 0) phi_p[w] = phi_r[0];
  if (h0 == 3) phi_p[65 * 64 + w] = phi_r[15];
#pragma unroll
  for (int off = 32; off; off >>= 1) sI += __shfl_xor(sI, off);
  if (w == 0) red[h0] = sI;
  __syncthreads();
  const float sumI = red[0] + red[1] + red[2] + red[3];
  __syncthreads();  // protect red[] before first in-iter reduction

  for (int it = 0; it < 10; ++it) {
    float s_at = 0.f, s_iat = 0.f;
#pragma unroll
    for (int k = 0; k < 16; ++k) {
      const float fyk = (k == 0) ? fy0 : ((k == 15) ? fy15 : 0.5f);
      float c = phi_r[k];
      float l = __shfl(c, wl), r = __shfl(c, wr);
      float u = phi_p[ib + k * 256];
      float d = phi_p[ib + 128 + k * 256];
      float px = (r - l) * fx;
      float py = (d - u) * fyk;
      float rn = __builtin_amdgcn_rsqf(fmaf(px, px, fmaf(py, py, 1e-8f)));
      float nxv = px * rn, nyv = py * rn;
      nx_r[k] = nxv;
      ny_p[ib + 64 + k * 256] = nyv;
      if (k == 0 && h0 == 0) ny_p[w] = nyv;
      if (k == 15 && h0 == 3) ny_p[65 * 64 + w] = nyv;
      float at = fast_atan(c);
      s_at += at;
      s_iat = fmaf(I[k], at, s_iat);
    }
#pragma unroll
    for (int off = 32; off; off >>= 1) {
      s_at += __shfl_xor(s_at, off);
      s_iat += __shfl_xor(s_iat, off);
    }
    if (w == 0) { red[h0 * 2] = s_at; red[h0 * 2 + 1] = s_iat; }
    __syncthreads();
    float S_at = red[0] + red[2] + red[4] + red[6];
    float S_iat = red[1] + red[3] + red[5] + red[7];
    float a1 = 2048.f + INV_PI * S_at;                  // sum H
    float sIH = fmaf(0.5f, sumI, INV_PI * S_iat);       // sum I*H
    float c1 = sIH / (a1 + 1e-8f);
    float c2 = (sumI - sIH) / (4096.f - a1 + 1e-8f);
    float lam12 = lam * (c1 - c2);
    float s12 = c1 + c2;
#pragma unroll
    for (int k = 0; k < 16; ++k) {
      const float fyk = (k == 0) ? fy0 : ((k == 15) ? fy15 : 0.5f);
      float nl = __shfl(nx_r[k], wl), nr = __shfl(nx_r[k], wr);
      float nu = ny_p[ib + k * 256];
      float nd = ny_p[ib + 128 + k * 256];
      float curv = fmaf(nd - nu, fyk, (nr - nl) * fx);
      float c = phi_r[k];
      float rcd = __builtin_amdgcn_rcpf(fmaf(c, c, 1.f));
      float force = fmaf(lam12, fmaf(2.f, I[k], -s12), curv);
      float npv = fmaf(dtpi * rcd, force, c);
      phi_r[k] = npv;
      phi_p[ib + 64 + k * 256] = npv;
      if (k == 0 && h0 == 0) phi_p[w] = npv;
      if (k == 15 && h0 == 3) phi_p[65 * 64 + w] = npv;
    }
    __syncthreads();
  }
#pragma unroll
  for (int k = 0; k < 16; ++k) {
    float e = exp2f(phi_r[k] * -1.44269504089f);
    ob[base + t + (k << 8)] = __builtin_amdgcn_rcpf(1.f + e);
  }
}

extern "C" void kernel_launch(void* const* d_in, const int* in_sizes, int n_in,
                              void* d_out, int out_size, void* d_ws, size_t ws_size,
                              hipStream_t stream)
{
  const float* contour = (const float*)d_in[0];
  const float* g       = (const float*)d_in[1];
  const float* x       = (const float*)d_in[2];
  const float* dt      = (const float*)d_in[3];
  const float* lam     = (const float*)d_in[4];
  const float* g_w     = (const float*)d_in[5];
  const float* x_w     = (const float*)d_in[6];
  const float* c_w     = (const float*)d_in[7];
  float* out = (float*)d_out;
  float* z   = (float*)d_ws;  // [8,512,64,64] f32 = 67 MB

  dim3 grid(32, 4, 8), blk(256);
  // z = relu(g * g_w^T) + x * x_w^T   (split-bf16 MFMA, ~fp32 accurate)
  mfma_gemm<<<grid, blk, 0, stream>>>(g_w, g, 256, 1, x_w, x, 512, z);
  // phi0 = contour * c_w^T -> d_out (iterated in place by chanvese)
  mfma_gemm<<<grid, blk, 0, stream>>>(c_w, contour, 256, 0, nullptr, nullptr, 0, out);
  // 10 Chan-Vese iterations + sigmoid, one block per (b,o) plane
  chanvese<<<dim3(4096), blk, 0, stream>>>(z, out, dt, lam);
}

// Round 3
// 335.864 us; speedup vs baseline: 2.1058x; 1.2111x over previous
//
#include <hip/hip_runtime.h>
#include <math.h>

#define PIX 4096
#define O_CH 512
#define LDS_PITCH 68

typedef __attribute__((ext_vector_type(8))) short s16x8;
typedef __attribute__((ext_vector_type(4))) float f32x4;

__device__ __forceinline__ ushort f2bf(float f) {
  unsigned u = __float_as_uint(f);
  return (ushort)((u + 0x7fffu + ((u >> 16) & 1u)) >> 16);
}
__device__ __forceinline__ float bf2f(ushort h) {
  return __uint_as_float(((unsigned)h) << 16);
}

// ---------------- MFMA GEMM (split-bf16, ~fp32 accurate) ----------------
__global__ __launch_bounds__(256, 2) void mfma_gemm(
    const float* __restrict__ W1, const float* __restrict__ A1b, int K1, int relu1,
    const float* __restrict__ W2, const float* __restrict__ A2b, int K2,
    float* __restrict__ out)
{
  __shared__ ushort WHs[8192], WLs[8192], AHs[8192], ALs[8192];  // 64 KB
  const int t = threadIdx.x;
  const int lane = t & 63, wave = t >> 6;
  const int wm = wave >> 1, wn = wave & 1;
  const int rowA = lane & 15, kg = lane >> 4;
  const int pb = blockIdx.x * 128, ob = blockIdx.y * 128, b = blockIdx.z;

  f32x4 acc[4][4];
#pragma unroll
  for (int mi = 0; mi < 4; ++mi)
#pragma unroll
    for (int ni = 0; ni < 4; ++ni) acc[mi][ni] = (f32x4){0.f, 0.f, 0.f, 0.f};

  for (int pass = 0; pass < 2; ++pass) {
    if (pass == 1 && W2 == nullptr) break;
    const float* W = pass ? W2 : W1;
    const int K = pass ? K2 : K1;
    const float* A = (pass ? A2b : A1b) + (size_t)b * K * PIX;

    for (int kb = 0; kb < K; kb += 64) {
      {
        const int o_r = t >> 1, hf = t & 1;
        const float* wrow = W + (size_t)(ob + o_r) * K + kb + hf * 32;
#pragma unroll
        for (int i = 0; i < 8; ++i) {
          float4 v = *(const float4*)(wrow + i * 4);
          ushort h0 = f2bf(v.x), h1 = f2bf(v.y), h2 = f2bf(v.z), h3 = f2bf(v.w);
          ushort l0 = f2bf(v.x - bf2f(h0)), l1 = f2bf(v.y - bf2f(h1));
          ushort l2 = f2bf(v.z - bf2f(h2)), l3 = f2bf(v.w - bf2f(h3));
          int grp = hf * 4 + (i >> 1);
          int idx = o_r * 64 + ((grp ^ (o_r & 7)) << 3) + (i & 1) * 4;
          *(ushort4*)&WHs[idx] = make_ushort4(h0, h1, h2, h3);
          *(ushort4*)&WLs[idx] = make_ushort4(l0, l1, l2, l3);
        }
      }
#pragma unroll
      for (int ph = 0; ph < 2; ++ph) {
        const int rp = ph * 64 + lane;
        const float* ac = A + (size_t)kb * PIX + pb + rp;
#pragma unroll
        for (int ch = 0; ch < 2; ++ch) {
          const int kloc0 = ch * 32 + wave * 8;
          float v[8];
#pragma unroll
          for (int j = 0; j < 8; ++j) v[j] = ac[(size_t)(kloc0 + j) * PIX];
          ushort hs[8], lsv[8];
#pragma unroll
          for (int j = 0; j < 8; ++j) {
            ushort hb = f2bf(v[j]);
            hs[j] = hb;
            lsv[j] = f2bf(v[j] - bf2f(hb));
          }
          int grp = ch * 4 + wave;
          int idx = rp * 64 + ((grp ^ (rp & 7)) << 3);
          *(ushort4*)&AHs[idx]     = make_ushort4(hs[0], hs[1], hs[2], hs[3]);
          *(ushort4*)&AHs[idx + 4] = make_ushort4(hs[4], hs[5], hs[6], hs[7]);
          *(ushort4*)&ALs[idx]     = make_ushort4(lsv[0], lsv[1], lsv[2], lsv[3]);
          *(ushort4*)&ALs[idx + 4] = make_ushort4(lsv[4], lsv[5], lsv[6], lsv[7]);
        }
      }
      __syncthreads();
#pragma unroll
      for (int ks = 0; ks < 2; ++ks) {
        s16x8 wh[4], wlv[4], ah[4], alv[4];
#pragma unroll
        for (int mi = 0; mi < 4; ++mi) {
          int row = wm * 64 + mi * 16 + rowA;
          int idx = row * 64 + (((ks * 4 + kg) ^ (row & 7)) << 3);
          wh[mi]  = *(const s16x8*)&WHs[idx];
          wlv[mi] = *(const s16x8*)&WLs[idx];
        }
#pragma unroll
        for (int ni = 0; ni < 4; ++ni) {
          int row = wn * 64 + ni * 16 + rowA;
          int idx = row * 64 + (((ks * 4 + kg) ^ (row & 7)) << 3);
          ah[ni]  = *(const s16x8*)&AHs[idx];
          alv[ni] = *(const s16x8*)&ALs[idx];
        }
#pragma unroll
        for (int mi = 0; mi < 4; ++mi)
#pragma unroll
          for (int ni = 0; ni < 4; ++ni) {
            acc[mi][ni] = __builtin_amdgcn_mfma_f32_16x16x32_bf16(wh[mi],  ah[ni],  acc[mi][ni], 0, 0, 0);
            acc[mi][ni] = __builtin_amdgcn_mfma_f32_16x16x32_bf16(wh[mi],  alv[ni], acc[mi][ni], 0, 0, 0);
            acc[mi][ni] = __builtin_amdgcn_mfma_f32_16x16x32_bf16(wlv[mi], ah[ni],  acc[mi][ni], 0, 0, 0);
          }
      }
      __syncthreads();
    }
    if (pass == 0 && relu1) {
#pragma unroll
      for (int mi = 0; mi < 4; ++mi)
#pragma unroll
        for (int ni = 0; ni < 4; ++ni)
#pragma unroll
          for (int r = 0; r < 4; ++r) acc[mi][ni][r] = fmaxf(acc[mi][ni][r], 0.f);
    }
  }
  const int orow = (lane >> 4) * 4, pcol = lane & 15;
#pragma unroll
  for (int mi = 0; mi < 4; ++mi)
#pragma unroll
    for (int ni = 0; ni < 4; ++ni)
#pragma unroll
      for (int r = 0; r < 4; ++r)
        out[((size_t)b * O_CH + ob + wm * 64 + mi * 16 + orow + r) * PIX +
            pb + wn * 64 + ni * 16 + pcol] = acc[mi][ni][r];
}

// ---------------- Chan-Vese: strip-per-thread, 10 iters in LDS/regs ----------------
__device__ __forceinline__ float fast_atan(float x) {
  float a = __builtin_fabsf(x);
  float inv = __builtin_amdgcn_rcpf(a);
  bool big = a > 1.f;
  float tt = big ? inv : a;
  float t2 = tt * tt;
  float p = fmaf(t2, 0.0208351f, -0.0851330f);
  p = fmaf(t2, p, 0.1801410f);
  p = fmaf(t2, p, -0.3302995f);
  p = fmaf(t2, p, 0.9998660f);
  p = p * tt;
  float r = big ? (1.57079632679f - p) : p;
  return __builtin_copysignf(r, x);
}

__global__ __launch_bounds__(256, 4) void chanvese(
    const float* __restrict__ zb, float* __restrict__ ob,
    const float* __restrict__ dtp, const float* __restrict__ lamp)
{
  __shared__ float phi_l[64 * LDS_PITCH];
  __shared__ float ny_l[64 * LDS_PITCH];
  __shared__ float red[12];
  const int t = threadIdx.x;
  const int lane = t & 63, wv = t >> 6;
  const int row = t >> 2, s = t & 3;
  const int col0 = s * 16;
  const size_t gbase = (size_t)blockIdx.x * PIX + row * 64 + col0;
  const float dtv = dtp[0], lam = lamp[0];
  const float INV_PI = 0.31830988618379067f;
  const float dtpi = dtv * INV_PI;
  const float fy = (row == 0 || row == 63) ? 1.f : 0.5f;
  const float fx0 = (s == 0) ? 1.f : 0.5f;
  const float fx15 = (s == 3) ? 1.f : 0.5f;
  const int my = row * LDS_PITCH + col0;
  const int ub = ((row == 0) ? 0 : row - 1) * LDS_PITCH + col0;
  const int db = ((row == 63) ? 63 : row + 1) * LDS_PITCH + col0;

  float I[16], phi[16], nx[16];
#pragma unroll
  for (int q = 0; q < 4; ++q) {
    float4 iv = *(const float4*)(zb + gbase + q * 4);
    float4 pv = *(const float4*)(ob + gbase + q * 4);
    I[q * 4 + 0] = iv.x; I[q * 4 + 1] = iv.y; I[q * 4 + 2] = iv.z; I[q * 4 + 3] = iv.w;
    phi[q * 4 + 0] = pv.x; phi[q * 4 + 1] = pv.y; phi[q * 4 + 2] = pv.z; phi[q * 4 + 3] = pv.w;
    *(float4*)&phi_l[my + q * 4] = pv;
  }
  // initial sums: sumI (loop-invariant) + atan sums of phi0
  float sI = 0.f, s_at = 0.f, s_iat = 0.f;
#pragma unroll
  for (int j = 0; j < 16; ++j) {
    sI += I[j];
    float at = fast_atan(phi[j]);
    s_at += at;
    s_iat = fmaf(I[j], at, s_iat);
  }
#pragma unroll
  for (int off = 32; off; off >>= 1) {
    sI += __shfl_xor(sI, off);
    s_at += __shfl_xor(s_at, off);
    s_iat += __shfl_xor(s_iat, off);
  }
  if (lane == 0) { red[2 * wv] = s_at; red[2 * wv + 1] = s_iat; red[8 + wv] = sI; }
  __syncthreads();
  const float sumI = red[8] + red[9] + red[10] + red[11];

  for (int it = 0; it < 10; ++it) {
    // region means from sums over current phi (written at end of prev iter / init)
    float S_at = red[0] + red[2] + red[4] + red[6];
    float S_iat = red[1] + red[3] + red[5] + red[7];
    float a1 = fmaf(INV_PI, S_at, 2048.f);
    float sIH = fmaf(INV_PI, S_iat, 0.5f * sumI);
    float c1 = sIH * __builtin_amdgcn_rcpf(a1 + 1e-8f);
    float c2 = (sumI - sIH) * __builtin_amdgcn_rcpf(4096.f - a1 + 1e-8f);
    float lam12 = lam * (c1 - c2);
    float s12 = c1 + c2;

    // ---- pass 1: normals ----
    float u[16], d[16], nyv[16];
#pragma unroll
    for (int q = 0; q < 4; ++q) {
      float4 uv = *(const float4*)&phi_l[ub + q * 4];
      float4 dv = *(const float4*)&phi_l[db + q * 4];
      u[q * 4 + 0] = uv.x; u[q * 4 + 1] = uv.y; u[q * 4 + 2] = uv.z; u[q * 4 + 3] = uv.w;
      d[q * 4 + 0] = dv.x; d[q * 4 + 1] = dv.y; d[q * 4 + 2] = dv.z; d[q * 4 + 3] = dv.w;
    }
    float ls = __shfl(phi[15], lane - 1);
    float rs = __shfl(phi[0], lane + 1);
#pragma unroll
    for (int j = 0; j < 16; ++j) {
      float l = (j == 0) ? ((s == 0) ? phi[0] : ls) : phi[j - 1];
      float r = (j == 15) ? ((s == 3) ? phi[15] : rs) : phi[j + 1];
      float fxj = (j == 0) ? fx0 : ((j == 15) ? fx15 : 0.5f);
      float px = (r - l) * fxj;
      float py = (d[j] - u[j]) * fy;
      float rn = __builtin_amdgcn_rsqf(fmaf(px, px, fmaf(py, py, 1e-8f)));
      nx[j] = px * rn;
      nyv[j] = py * rn;
    }
#pragma unroll
    for (int q = 0; q < 4; ++q)
      *(float4*)&ny_l[my + q * 4] =
          make_float4(nyv[q * 4], nyv[q * 4 + 1], nyv[q * 4 + 2], nyv[q * 4 + 3]);
    __syncthreads();

    // ---- pass 2: curvature + update + next-iter sums ----
    float nyu[16], nyd[16];
#pragma unroll
    for (int q = 0; q < 4; ++q) {
      float4 uv = *(const float4*)&ny_l[ub + q * 4];
      float4 dv = *(const float4*)&ny_l[db + q * 4];
      nyu[q * 4 + 0] = uv.x; nyu[q * 4 + 1] = uv.y; nyu[q * 4 + 2] = uv.z; nyu[q * 4 + 3] = uv.w;
      nyd[q * 4 + 0] = dv.x; nyd[q * 4 + 1] = dv.y; nyd[q * 4 + 2] = dv.z; nyd[q * 4 + 3] = dv.w;
    }
    float nls = __shfl(nx[15], lane - 1);
    float nrs = __shfl(nx[0], lane + 1);
    s_at = 0.f; s_iat = 0.f;
#pragma unroll
    for (int j = 0; j < 16; ++j) {
      float nl = (j == 0) ? ((s == 0) ? nx[0] : nls) : nx[j - 1];
      float nr = (j == 15) ? ((s == 3) ? nx[15] : nrs) : nx[j + 1];
      float fxj = (j == 0) ? fx0 : ((j == 15) ? fx15 : 0.5f);
      float curv = fmaf(nyd[j] - nyu[j], fy, (nr - nl) * fxj);
      float c = phi[j];
      float rcd = __builtin_amdgcn_rcpf(fmaf(c, c, 1.f));
      float force = fmaf(lam12, fmaf(2.f, I[j], -s12), curv);
      float pn = fmaf(dtpi * rcd, force, c);
      phi[j] = pn;
      float at = fast_atan(pn);
      s_at += at;
      s_iat = fmaf(I[j], at, s_iat);
    }
#pragma unroll
    for (int q = 0; q < 4; ++q)
      *(float4*)&phi_l[my + q * 4] =
          make_float4(phi[q * 4], phi[q * 4 + 1], phi[q * 4 + 2], phi[q * 4 + 3]);
#pragma unroll
    for (int off = 32; off; off >>= 1) {
      s_at += __shfl_xor(s_at, off);
      s_iat += __shfl_xor(s_iat, off);
    }
    if (lane == 0) { red[2 * wv] = s_at; red[2 * wv + 1] = s_iat; }
    __syncthreads();
  }

#pragma unroll
  for (int q = 0; q < 4; ++q) {
    float o0 = 1.f / (1.f + exp2f(phi[q * 4 + 0] * -1.44269504089f));
    float o1 = 1.f / (1.f + exp2f(phi[q * 4 + 1] * -1.44269504089f));
    float o2 = 1.f / (1.f + exp2f(phi[q * 4 + 2] * -1.44269504089f));
    float o3 = 1.f / (1.f + exp2f(phi[q * 4 + 3] * -1.44269504089f));
    *(float4*)(ob + gbase + q * 4) = make_float4(o0, o1, o2, o3);
  }
}

extern "C" void kernel_launch(void* const* d_in, const int* in_sizes, int n_in,
                              void* d_out, int out_size, void* d_ws, size_t ws_size,
                              hipStream_t stream)
{
  const float* contour = (const float*)d_in[0];
  const float* g       = (const float*)d_in[1];
  const float* x       = (const float*)d_in[2];
  const float* dt      = (const float*)d_in[3];
  const float* lam     = (const float*)d_in[4];
  const float* g_w     = (const float*)d_in[5];
  const float* x_w     = (const float*)d_in[6];
  const float* c_w     = (const float*)d_in[7];
  float* out = (float*)d_out;
  float* z   = (float*)d_ws;  // [8,512,64,64] f32 = 67 MB

  dim3 grid(32, 4, 8), blk(256);
  mfma_gemm<<<grid, blk, 0, stream>>>(g_w, g, 256, 1, x_w, x, 512, z);
  mfma_gemm<<<grid, blk, 0, stream>>>(c_w, contour, 256, 0, nullptr, nullptr, 0, out);
  chanvese<<<dim3(4096), blk, 0, stream>>>(z, out, dt, lam);
}